// Round 1
// baseline (24731.987 us; speedup 1.0000x reference)
//
#include <hip/hip_runtime.h>

namespace {
constexpr int T    = 2048;
constexpr int B    = 4096;
constexpr int H    = 51;
constexpr int IN   = 2;
constexpr int UPAD = 52;   // padded unit rows (row 51 = zeros)
constexpr int NB   = 16;   // batches per block
constexpr int BLK  = 256;  // threads per block (4 waves, 1 batch-quad each)
constexpr int GRID = B / NB; // 256

// LDS layout (float offsets)
constexpr int SZ_W1I = 2 * UPAD * 4;        // [k=2][UPAD][4 gates]
constexpr int SZ_WH  = H * UPAD * 4;        // [k=51][UPAD][4 gates]
constexpr int OFF_W1I = 0;
constexpr int OFF_W1H = OFF_W1I + SZ_W1I;
constexpr int OFF_W2I = OFF_W1H + SZ_WH;
constexpr int OFF_W2H = OFF_W2I + SZ_WH;
constexpr int OFF_B1  = OFF_W2H + SZ_WH;    // [UPAD][4]
constexpr int OFF_B2  = OFF_B1 + UPAD * 4;
constexpr int OFF_WL  = OFF_B2 + UPAD * 4;  // [64]
constexpr int OFF_H1  = OFF_WL + 64;        // [2][UPAD][NB]
constexpr int OFF_H2  = OFF_H1 + 2 * UPAD * NB;
constexpr int LDS_FLOATS = OFF_H2 + 2 * UPAD * NB;
}

#define FMA4(A, WS, HV)                      \
  A.x = fmaf((WS), (HV).x, A.x);             \
  A.y = fmaf((WS), (HV).y, A.y);             \
  A.z = fmaf((WS), (HV).z, A.z);             \
  A.w = fmaf((WS), (HV).w, A.w)

__device__ __forceinline__ float sigm(float v) {
  // 1/(1+exp(-v)); v very negative -> exp(+|v|)=inf -> 1/inf = 0, safe
  return 1.0f / (1.0f + __expf(-v));
}
__device__ __forceinline__ float tanh_fast(float v) {
  // symmetric form: e = exp(-2|v|) in (0,1], never overflows
  float e = __expf(-2.0f * fabsf(v));
  float r = (1.0f - e) / (1.0f + e);
  return copysignf(r, v);
}

__global__ __launch_bounds__(BLK) void lstm2_kernel(
    const float* __restrict__ x,
    const float* __restrict__ Wih1, const float* __restrict__ Whh1,
    const float* __restrict__ bih1, const float* __restrict__ bhh1,
    const float* __restrict__ Wih2, const float* __restrict__ Whh2,
    const float* __restrict__ bih2, const float* __restrict__ bhh2,
    const float* __restrict__ Wlin, const float* __restrict__ blin,
    float* __restrict__ out) {
  extern __shared__ float sm[];
  const int tid = threadIdx.x;

  // ---- stage weights into LDS, repacked as [k][u][gate] with zero pad row ----
  for (int idx = tid; idx < SZ_W1I; idx += BLK) {
    int k = idx / (UPAD * 4); int r = idx % (UPAD * 4);
    int uu = r >> 2; int g = r & 3;
    sm[OFF_W1I + idx] = (uu < H) ? Wih1[(g * H + uu) * IN + k] : 0.0f;
  }
  for (int idx = tid; idx < SZ_WH; idx += BLK) {
    int k = idx / (UPAD * 4); int r = idx % (UPAD * 4);
    int uu = r >> 2; int g = r & 3;
    float v1 = 0.0f, v2 = 0.0f, v3 = 0.0f;
    if (uu < H) {
      int row = g * H + uu;
      v1 = Whh1[row * H + k];
      v2 = Wih2[row * H + k];
      v3 = Whh2[row * H + k];
    }
    sm[OFF_W1H + idx] = v1;
    sm[OFF_W2I + idx] = v2;
    sm[OFF_W2H + idx] = v3;
  }
  for (int idx = tid; idx < UPAD * 4; idx += BLK) {
    int uu = idx >> 2; int g = idx & 3;
    float b1 = 0.0f, b2 = 0.0f;
    if (uu < H) {
      b1 = bih1[g * H + uu] + bhh1[g * H + uu];
      b2 = bih2[g * H + uu] + bhh2[g * H + uu];
    }
    sm[OFF_B1 + idx] = b1;
    sm[OFF_B2 + idx] = b2;
  }
  if (tid < 64) sm[OFF_WL + tid] = (tid < H) ? Wlin[tid] : 0.0f;
  for (int idx = tid; idx < 4 * UPAD * NB; idx += BLK) sm[OFF_H1 + idx] = 0.0f;
  __syncthreads();

  const int u  = tid & 63;                    // hidden unit (51 active)
  const int wq = tid >> 6;                    // wave id = batch quad 0..3
  const int uc = (u < UPAD) ? u : (UPAD - 1); // clamp pad lanes to zero row
  const int b0 = blockIdx.x * NB + wq * 4;
  const bool act = (u < H);
  const float bl = blin[0];

  float4 c1 = {0.f, 0.f, 0.f, 0.f};
  float4 c2 = {0.f, 0.f, 0.f, 0.f};

  int cur = 0;
  float4 xv0 = *(const float4*)(x + (size_t)(0 * B + b0) * IN);
  float4 xv1 = *(const float4*)(x + (size_t)(0 * B + b0) * IN + 4);

  for (int t = 0; t < T; ++t) {
    // prefetch next step's x (uniform per wave)
    int tn = (t + 1 < T) ? (t + 1) : t;
    float4 xn0 = *(const float4*)(x + (size_t)(tn * B + b0) * IN);
    float4 xn1 = *(const float4*)(x + (size_t)(tn * B + b0) * IN + 4);

    // ================= layer 1 =================
    float4 bv = *(const float4*)&sm[OFF_B1 + uc * 4];
    float4 ai = {bv.x, bv.x, bv.x, bv.x};
    float4 af = {bv.y, bv.y, bv.y, bv.y};
    float4 ag = {bv.z, bv.z, bv.z, bv.z};
    float4 ao = {bv.w, bv.w, bv.w, bv.w};

    {  // input contribution: IN=2
      float4 w0 = *(const float4*)&sm[OFF_W1I + (0 * UPAD + uc) * 4];
      float4 w1 = *(const float4*)&sm[OFF_W1I + (1 * UPAD + uc) * 4];
      float4 xj0 = {xv0.x, xv0.z, xv1.x, xv1.z};  // in-feature 0 per batch j
      float4 xj1 = {xv0.y, xv0.w, xv1.y, xv1.w};  // in-feature 1 per batch j
      FMA4(ai, w0.x, xj0); FMA4(ai, w1.x, xj1);
      FMA4(af, w0.y, xj0); FMA4(af, w1.y, xj1);
      FMA4(ag, w0.z, xj0); FMA4(ag, w1.z, xj1);
      FMA4(ao, w0.w, xj0); FMA4(ao, w1.w, xj1);
    }

#pragma unroll 17
    for (int k = 0; k < H; ++k) {
      float4 w  = *(const float4*)&sm[OFF_W1H + (k * UPAD + uc) * 4];
      float4 hv = *(const float4*)&sm[OFF_H1 + (cur * UPAD + k) * NB + wq * 4];
      FMA4(ai, w.x, hv); FMA4(af, w.y, hv);
      FMA4(ag, w.z, hv); FMA4(ao, w.w, hv);
    }

    float4 h1v;
    c1.x = sigm(af.x) * c1.x + sigm(ai.x) * tanh_fast(ag.x); h1v.x = sigm(ao.x) * tanh_fast(c1.x);
    c1.y = sigm(af.y) * c1.y + sigm(ai.y) * tanh_fast(ag.y); h1v.y = sigm(ao.y) * tanh_fast(c1.y);
    c1.z = sigm(af.z) * c1.z + sigm(ai.z) * tanh_fast(ag.z); h1v.z = sigm(ao.z) * tanh_fast(c1.z);
    c1.w = sigm(af.w) * c1.w + sigm(ai.w) * tanh_fast(ag.w); h1v.w = sigm(ao.w) * tanh_fast(c1.w);

    if (act) *(float4*)&sm[OFF_H1 + ((cur ^ 1) * UPAD + u) * NB + wq * 4] = h1v;
    __syncthreads();

    // ================= layer 2 =================
    bv = *(const float4*)&sm[OFF_B2 + uc * 4];
    ai = make_float4(bv.x, bv.x, bv.x, bv.x);
    af = make_float4(bv.y, bv.y, bv.y, bv.y);
    ag = make_float4(bv.z, bv.z, bv.z, bv.z);
    ao = make_float4(bv.w, bv.w, bv.w, bv.w);

#pragma unroll 3
    for (int k = 0; k < H; ++k) {
      float4 wi = *(const float4*)&sm[OFF_W2I + (k * UPAD + uc) * 4];
      float4 wh = *(const float4*)&sm[OFF_W2H + (k * UPAD + uc) * 4];
      float4 hi = *(const float4*)&sm[OFF_H1 + ((cur ^ 1) * UPAD + k) * NB + wq * 4];
      float4 hh = *(const float4*)&sm[OFF_H2 + (cur * UPAD + k) * NB + wq * 4];
      FMA4(ai, wi.x, hi); FMA4(ai, wh.x, hh);
      FMA4(af, wi.y, hi); FMA4(af, wh.y, hh);
      FMA4(ag, wi.z, hi); FMA4(ag, wh.z, hh);
      FMA4(ao, wi.w, hi); FMA4(ao, wh.w, hh);
    }

    float4 h2v;
    c2.x = sigm(af.x) * c2.x + sigm(ai.x) * tanh_fast(ag.x); h2v.x = sigm(ao.x) * tanh_fast(c2.x);
    c2.y = sigm(af.y) * c2.y + sigm(ai.y) * tanh_fast(ag.y); h2v.y = sigm(ao.y) * tanh_fast(c2.y);
    c2.z = sigm(af.z) * c2.z + sigm(ai.z) * tanh_fast(ag.z); h2v.z = sigm(ao.z) * tanh_fast(c2.z);
    c2.w = sigm(af.w) * c2.w + sigm(ai.w) * tanh_fast(ag.w); h2v.w = sigm(ao.w) * tanh_fast(c2.w);

    if (act) *(float4*)&sm[OFF_H2 + ((cur ^ 1) * UPAD + u) * NB + wq * 4] = h2v;

    // ---- linear head: out[b][t] = sum_u Wlin[u]*h2[u] + blin ----
    float wl = sm[OFF_WL + u];  // zero for pad lanes
    float s0 = wl * h2v.x, s1 = wl * h2v.y, s2 = wl * h2v.z, s3 = wl * h2v.w;
#pragma unroll
    for (int m = 1; m < 64; m <<= 1) {
      s0 += __shfl_xor(s0, m, 64);
      s1 += __shfl_xor(s1, m, 64);
      s2 += __shfl_xor(s2, m, 64);
      s3 += __shfl_xor(s3, m, 64);
    }
    if (u == 0) {
      out[(size_t)(b0 + 0) * T + t] = s0 + bl;
      out[(size_t)(b0 + 1) * T + t] = s1 + bl;
      out[(size_t)(b0 + 2) * T + t] = s2 + bl;
      out[(size_t)(b0 + 3) * T + t] = s3 + bl;
    }
    __syncthreads();

    cur ^= 1;
    xv0 = xn0; xv1 = xn1;
  }
}

extern "C" void kernel_launch(void* const* d_in, const int* in_sizes, int n_in,
                              void* d_out, int out_size, void* d_ws, size_t ws_size,
                              hipStream_t stream) {
  (void)in_sizes; (void)n_in; (void)d_ws; (void)ws_size; (void)out_size;
  const float* x    = (const float*)d_in[0];
  const float* Wih1 = (const float*)d_in[1];
  const float* Whh1 = (const float*)d_in[2];
  const float* bih1 = (const float*)d_in[3];
  const float* bhh1 = (const float*)d_in[4];
  const float* Wih2 = (const float*)d_in[5];
  const float* Whh2 = (const float*)d_in[6];
  const float* bih2 = (const float*)d_in[7];
  const float* bhh2 = (const float*)d_in[8];
  const float* Wlin = (const float*)d_in[9];
  const float* blin = (const float*)d_in[10];
  float* out = (float*)d_out;

  size_t shmem = (size_t)LDS_FLOATS * sizeof(float);
  // >64KB dynamic LDS: opt in (idempotent, host-side, graph-capture safe)
  hipFuncSetAttribute((const void*)lstm2_kernel,
                      hipFuncAttributeMaxDynamicSharedMemorySize, (int)shmem);

  hipLaunchKernelGGL(lstm2_kernel, dim3(GRID), dim3(BLK), shmem, stream,
                     x, Wih1, Whh1, bih1, bhh1, Wih2, Whh2, bih2, bhh2,
                     Wlin, blin, out);
}

// Round 2
// 6709.174 us; speedup vs baseline: 3.6863x; 3.6863x over previous
//
#include <hip/hip_runtime.h>

namespace {
constexpr int T   = 2048;
constexpr int Bsz = 4096;
constexpr int H   = 51;    // hidden units; gate rows = 4*H = 204
constexpr int IN  = 2;
constexpr int NB  = 16;    // batches per block (= MFMA M dim)
constexpr int BLK = 256;   // 4 waves
constexpr int GRID = Bsz / NB;  // 256
constexpr int GS  = 18;    // GATES row stride (floats), b64-aligned, ~4-way max
}

typedef float f32x4 __attribute__((ext_vector_type(4)));
typedef short s16x8 __attribute__((ext_vector_type(8)));

__device__ __forceinline__ unsigned short f2bf(float f) {
  unsigned u = __float_as_uint(f);
  unsigned r = (u + 0x7FFFu + ((u >> 16) & 1u)) >> 16;  // RNE
  return (unsigned short)r;
}
__device__ __forceinline__ float bf2f(unsigned short h) {
  return __uint_as_float(((unsigned)h) << 16);
}
__device__ __forceinline__ float sigm(float v) { return 1.0f / (1.0f + __expf(-v)); }
__device__ __forceinline__ float tanh_fast(float v) {
  float e = __expf(-2.0f * fabsf(v));
  float r = (1.0f - e) / (1.0f + e);
  return copysignf(r, v);
}

#define SPLIT_STORE(dsthi, dstlo, vexpr)          \
  { float v_ = (vexpr);                           \
    unsigned short hb_ = f2bf(v_);                \
    (dsthi)[j] = (short)hb_;                      \
    (dstlo)[j] = (short)f2bf(v_ - bf2f(hb_)); }

#define MFMA4(D, AH, AL, BH, BL)                                              \
  D = __builtin_amdgcn_mfma_f32_16x16x32_bf16(AH, BH, D, 0, 0, 0);            \
  D = __builtin_amdgcn_mfma_f32_16x16x32_bf16(AH, BL, D, 0, 0, 0);            \
  D = __builtin_amdgcn_mfma_f32_16x16x32_bf16(AL, BH, D, 0, 0, 0);            \
  D = __builtin_amdgcn_mfma_f32_16x16x32_bf16(AL, BL, D, 0, 0, 0);

__global__ __launch_bounds__(BLK, 1) void lstm2_mfma(
    const float* __restrict__ x,
    const float* __restrict__ Wih1, const float* __restrict__ Whh1,
    const float* __restrict__ bih1, const float* __restrict__ bhh1,
    const float* __restrict__ Wih2, const float* __restrict__ Whh2,
    const float* __restrict__ bih2, const float* __restrict__ bhh2,
    const float* __restrict__ Wlin, const float* __restrict__ blin,
    float* __restrict__ out) {
  // SMEM: weight staging at init (204*51 floats), then GATES[256][GS] (4608 floats)
  __shared__ __align__(16) float SMEM[204 * 51];
  __shared__ __align__(16) unsigned short PH1HI[1024], PH1LO[1024];
  __shared__ __align__(16) unsigned short PH2HI[1024], PH2LO[1024];

  const int tid  = threadIdx.x;
  const int lane = tid & 63;
  const int wid  = tid >> 6;       // wave: MFMA role = gate wid; ew role = batch-quad wid
  const int a    = lane & 15;      // MFMA col-within-tile / A batch row
  const int q    = lane >> 4;      // MFMA k-block / D row-quad

  // ---- zero h-fragment planes; set A1[k=51] = 1.0 (bias lane) for all 16 batches ----
  for (int i = tid; i < 1024; i += BLK) { PH1HI[i]=0; PH1LO[i]=0; PH2HI[i]=0; PH2LO[i]=0; }
  if (tid < 16) PH1HI[512 + tid*8 + 7] = 0x3F80;  // k=51 -> (s=1,kl=19) -> lane=b, j=7

  // ---- build weight B-fragments in registers (hi/lo bf16 split) ----
  s16x8 b1h[4][2], b1l[4][2];   // L1: Whh1 + bias1 @k=51 ; tiles i, ksteps s
  s16x8 b2h[4][4], b2l[4][4];   // L2: s<2: Wih2 + bias2 @k=51 ; s>=2: Whh2

  for (int i = tid; i < 204*51; i += BLK) SMEM[i] = Whh1[i];
  __syncthreads();
#pragma unroll
  for (int i = 0; i < 4; ++i) {
    const int uu = 16*i + a;
    const int r  = wid*H + uu;
#pragma unroll
    for (int s = 0; s < 2; ++s) {
#pragma unroll
      for (int j = 0; j < 8; ++j) {
        const int k = 32*s + ((j>>2)<<4) + (q<<2) + (j&3);
        float v = 0.f;
        if (uu < H) {
          if (k < H) v = SMEM[r*H + k];
          else if (k == H) v = bih1[r] + bhh1[r];
        }
        SPLIT_STORE(b1h[i][s], b1l[i][s], v);
      }
    }
  }
  __syncthreads();
  for (int i = tid; i < 204*51; i += BLK) SMEM[i] = Wih2[i];
  __syncthreads();
#pragma unroll
  for (int i = 0; i < 4; ++i) {
    const int uu = 16*i + a;
    const int r  = wid*H + uu;
#pragma unroll
    for (int s = 0; s < 2; ++s) {
#pragma unroll
      for (int j = 0; j < 8; ++j) {
        const int k = 32*s + ((j>>2)<<4) + (q<<2) + (j&3);
        float v = 0.f;
        if (uu < H) {
          if (k < H) v = SMEM[r*H + k];
          else if (k == H) v = bih2[r] + bhh2[r];
        }
        SPLIT_STORE(b2h[i][s], b2l[i][s], v);
      }
    }
  }
  __syncthreads();
  for (int i = tid; i < 204*51; i += BLK) SMEM[i] = Whh2[i];
  __syncthreads();
#pragma unroll
  for (int i = 0; i < 4; ++i) {
    const int uu = 16*i + a;
    const int r  = wid*H + uu;
#pragma unroll
    for (int s = 2; s < 4; ++s) {
#pragma unroll
      for (int j = 0; j < 8; ++j) {
        const int k = 32*(s-2) + ((j>>2)<<4) + (q<<2) + (j&3);
        float v = 0.f;
        if (uu < H && k < H) v = SMEM[r*H + k];
        SPLIT_STORE(b2h[i][s], b2l[i][s], v);
      }
    }
  }
  __syncthreads();  // SMEM now free -> becomes GATES

  // ---- elementwise-role constants ----
  const int u = lane;
  float wihr[8], wl;
#pragma unroll
  for (int g = 0; g < 4; ++g)
#pragma unroll
    for (int in = 0; in < 2; ++in)
      wihr[g*2+in] = (u < H) ? Wih1[(g*H + u)*IN + in] : 0.f;
  wl = (u < H) ? Wlin[u] : 0.f;
  const float bl = blin[0];
  const bool hAct = (u < H);
  int hIdx[4];
  {
    const int s = u >> 5, kl = u & 31;
    const int j = (kl & 3) + 4*(kl >> 4);
    const int lpb = 16*((kl >> 2) & 3);
#pragma unroll
    for (int r = 0; r < 4; ++r) hIdx[r] = s*512 + (wid*4 + r + lpb)*8 + j;
  }
  const int gBase = u*GS + wid*4;            // + g*64*GS per gate
  const int wBase = wid*64*GS + a*GS + q*4;  // + i*16*GS per tile
  const int b0g   = blockIdx.x * NB + wid*4;

  float c1[4] = {0,0,0,0}, c2[4] = {0,0,0,0};

  // initial A1 fragments (h1 = 0, bias lane = 1)
  s16x8 a1h[2], a1l[2];
#pragma unroll
  for (int s = 0; s < 2; ++s) {
    a1h[s] = *(const s16x8*)&PH1HI[s*512 + lane*8];
    a1l[s] = *(const s16x8*)&PH1LO[s*512 + lane*8];
  }
  float xv[8], xn[8];
#pragma unroll
  for (int r = 0; r < 4; ++r) {
    float2 t2 = *(const float2*)(x + ((size_t)(b0g + r))*IN);
    xv[2*r] = t2.x; xv[2*r+1] = t2.y;
  }

  for (int t = 0; t < T; ++t) {
    // ================= stage A: L1 MFMA (gates1 = A1 * B1) =================
    f32x4 dd[4];
#pragma unroll
    for (int i = 0; i < 4; ++i) dd[i] = (f32x4){0.f,0.f,0.f,0.f};
#pragma unroll
    for (int s = 0; s < 2; ++s)
#pragma unroll
      for (int i = 0; i < 4; ++i) { MFMA4(dd[i], a1h[s], a1l[s], b1h[i][s], b1l[i][s]); }
#pragma unroll
    for (int i = 0; i < 4; ++i) {
      *(float2*)&SMEM[wBase + i*16*GS]     = make_float2(dd[i].x, dd[i].y);
      *(float2*)&SMEM[wBase + i*16*GS + 2] = make_float2(dd[i].z, dd[i].w);
    }
    __syncthreads();

    // ================= stage B: elementwise L1 =================
    float gv[4][4];
#pragma unroll
    for (int g = 0; g < 4; ++g)
#pragma unroll
      for (int p = 0; p < 2; ++p) {
        float2 t2 = *(const float2*)&SMEM[g*64*GS + gBase + 2*p];
        gv[g][2*p] = t2.x; gv[g][2*p+1] = t2.y;
      }
    float h1v[4];
#pragma unroll
    for (int r = 0; r < 4; ++r) {
      const float x0 = xv[2*r], x1 = xv[2*r+1];
      const float gi = gv[0][r] + wihr[0]*x0 + wihr[1]*x1;
      const float gf = gv[1][r] + wihr[2]*x0 + wihr[3]*x1;
      const float gg = gv[2][r] + wihr[4]*x0 + wihr[5]*x1;
      const float go = gv[3][r] + wihr[6]*x0 + wihr[7]*x1;
      c1[r] = sigm(gf)*c1[r] + sigm(gi)*tanh_fast(gg);
      h1v[r] = sigm(go)*tanh_fast(c1[r]);
    }
    if (hAct) {
#pragma unroll
      for (int r = 0; r < 4; ++r) {
        unsigned short hb = f2bf(h1v[r]);
        PH1HI[hIdx[r]] = hb;
        PH1LO[hIdx[r]] = f2bf(h1v[r] - bf2f(hb));
      }
    }
    { // prefetch next-step x
      const int tn = (t+1 < T) ? (t+1) : t;
#pragma unroll
      for (int r = 0; r < 4; ++r) {
        float2 t2 = *(const float2*)(x + ((size_t)tn*Bsz + b0g + r)*IN);
        xn[2*r] = t2.x; xn[2*r+1] = t2.y;
      }
    }
    __syncthreads();

    // ================= stage C: L2 MFMA (gates2 = [h1new,1 | h2,0] * B2) =================
    s16x8 a2h[4], a2l[4];
#pragma unroll
    for (int s = 0; s < 2; ++s) {
      a2h[s]   = *(const s16x8*)&PH1HI[s*512 + lane*8];
      a2l[s]   = *(const s16x8*)&PH1LO[s*512 + lane*8];
      a2h[2+s] = *(const s16x8*)&PH2HI[s*512 + lane*8];
      a2l[2+s] = *(const s16x8*)&PH2LO[s*512 + lane*8];
    }
#pragma unroll
    for (int i = 0; i < 4; ++i) dd[i] = (f32x4){0.f,0.f,0.f,0.f};
#pragma unroll
    for (int s = 0; s < 4; ++s)
#pragma unroll
      for (int i = 0; i < 4; ++i) { MFMA4(dd[i], a2h[s], a2l[s], b2h[i][s], b2l[i][s]); }
#pragma unroll
    for (int i = 0; i < 4; ++i) {
      *(float2*)&SMEM[wBase + i*16*GS]     = make_float2(dd[i].x, dd[i].y);
      *(float2*)&SMEM[wBase + i*16*GS + 2] = make_float2(dd[i].z, dd[i].w);
    }
    __syncthreads();

    // ================= stage D: elementwise L2 + output head =================
#pragma unroll
    for (int g = 0; g < 4; ++g)
#pragma unroll
      for (int p = 0; p < 2; ++p) {
        float2 t2 = *(const float2*)&SMEM[g*64*GS + gBase + 2*p];
        gv[g][2*p] = t2.x; gv[g][2*p+1] = t2.y;
      }
    float h2v[4];
#pragma unroll
    for (int r = 0; r < 4; ++r) {
      c2[r] = sigm(gv[1][r])*c2[r] + sigm(gv[0][r])*tanh_fast(gv[2][r]);
      h2v[r] = sigm(gv[3][r])*tanh_fast(c2[r]);
    }
    if (hAct) {
#pragma unroll
      for (int r = 0; r < 4; ++r) {
        unsigned short hb = f2bf(h2v[r]);
        PH2HI[hIdx[r]] = hb;
        PH2LO[hIdx[r]] = f2bf(h2v[r] - bf2f(hb));
      }
    }
    float s0 = wl*h2v[0], s1 = wl*h2v[1], s2 = wl*h2v[2], s3 = wl*h2v[3];
#pragma unroll
    for (int m = 1; m < 64; m <<= 1) {
      s0 += __shfl_xor(s0, m);
      s1 += __shfl_xor(s1, m);
      s2 += __shfl_xor(s2, m);
      s3 += __shfl_xor(s3, m);
    }
    if (u == 0) {
      out[(size_t)(b0g + 0)*T + t] = s0 + bl;
      out[(size_t)(b0g + 1)*T + t] = s1 + bl;
      out[(size_t)(b0g + 2)*T + t] = s2 + bl;
      out[(size_t)(b0g + 3)*T + t] = s3 + bl;
    }
    // carry: A1(t+1) = h1new fragments already in regs; roll x prefetch
#pragma unroll
    for (int s = 0; s < 2; ++s) { a1h[s] = a2h[s]; a1l[s] = a2l[s]; }
#pragma unroll
    for (int r = 0; r < 8; ++r) xv[r] = xn[r];
    __syncthreads();
  }
}

extern "C" void kernel_launch(void* const* d_in, const int* in_sizes, int n_in,
                              void* d_out, int out_size, void* d_ws, size_t ws_size,
                              hipStream_t stream) {
  (void)in_sizes; (void)n_in; (void)d_ws; (void)ws_size; (void)out_size;
  const float* x    = (const float*)d_in[0];
  const float* Wih1 = (const float*)d_in[1];
  const float* Whh1 = (const float*)d_in[2];
  const float* bih1 = (const float*)d_in[3];
  const float* bhh1 = (const float*)d_in[4];
  const float* Wih2 = (const float*)d_in[5];
  const float* Whh2 = (const float*)d_in[6];
  const float* bih2 = (const float*)d_in[7];
  const float* bhh2 = (const float*)d_in[8];
  const float* Wlin = (const float*)d_in[9];
  const float* blin = (const float*)d_in[10];
  float* out = (float*)d_out;

  hipLaunchKernelGGL(lstm2_mfma, dim3(GRID), dim3(BLK), 0, stream,
                     x, Wih1, Whh1, bih1, bhh1, Wih2, Whh2, bih2, bhh2,
                     Wlin, blin, out);
}

// Round 3
// 2064.553 us; speedup vs baseline: 11.9793x; 3.2497x over previous
//
#include <hip/hip_runtime.h>

namespace {
constexpr int T    = 2048;
constexpr int Bsz  = 4096;
constexpr int H    = 51;     // hidden units
constexpr int H4   = 204;    // 4*H gate rows
constexpr int NB   = 16;     // batches per block = MFMA free dim
constexpr int BLK  = 512;    // 8 waves
constexpr int GRID = Bsz / NB;  // 256 blocks = 1/CU
}

typedef float    f32x4 __attribute__((ext_vector_type(4)));
typedef _Float16 f16x8 __attribute__((ext_vector_type(8)));
typedef unsigned short u16;

__device__ __forceinline__ float RCP(float x) { return __builtin_amdgcn_rcpf(x); }

// PyTorch LSTM cell: i,f,g,o = gates; c = sigm(f)*c + sigm(i)*tanh(g); h = sigm(o)*tanh(c)
// Fused: sigm(i)*tanh(g) = sign(g)*(1-eg)/((1+ei)(1+eg));  sigm(o)*tanh(c) likewise.
// 5 exp + 3 rcp per cell (v_exp/v_rcp quarter-rate; no precise-div chains).
__device__ __forceinline__ float lstm_act(float gi, float gf, float gg, float go, float& c) {
  float ei = __expf(-gi);
  float ef = __expf(-gf);
  float eo = __expf(-go);
  float eg = __expf(-2.0f * fabsf(gg));
  float sf = RCP(1.0f + ef);
  float ig = copysignf(1.0f - eg, gg) * RCP((1.0f + ei) * (1.0f + eg));
  c = sf * c + ig;
  float ec = __expf(-2.0f * fabsf(c));
  return copysignf(1.0f - ec, c) * RCP((1.0f + eo) * (1.0f + ec));
}

// Fragment k-mapping (validated in round 2, identical for A and B sides):
//   lane = free_idx(0..15) + 16*q ;  element j in [0,8) :  k = 32*sp + 16*(j>>2) + 4*q + (j&3)
// h-plane layout (validated round 2): value (b, k): sp=k>>5, kl=k&31,
//   row = b + 16*((kl>>2)&3), j = (kl&3) + 4*(kl>>4); lane L reads shorts [L*8..L*8+8).
// Plane arena PL (shorts): [buf(2)][layer(2)][sp(2)][row(64)][j(8)]  -> 4096 shorts = 8KB.
// K-slot assignment layer1: k<51 h1 | k=51 x0 | k=52 x1 | k=53 const 1 (bias row)
//               layer2 (k'=k-64): k'<51 h2 | k'=53 const 1 (head bias row)

__global__ __launch_bounds__(BLK, 2) void lstm2_v3(
    const float* __restrict__ x,
    const float* __restrict__ Wih1, const float* __restrict__ Whh1,
    const float* __restrict__ bih1, const float* __restrict__ bhh1,
    const float* __restrict__ Wih2, const float* __restrict__ Whh2,
    const float* __restrict__ bih2, const float* __restrict__ bhh2,
    const float* __restrict__ Wlin, const float* __restrict__ blin,
    float* __restrict__ out) {
  __shared__ __align__(16) float SW[H4 * H];   // 41.6 KB weight staging (init only)
  __shared__ __align__(16) u16   PL[4096];     // 8 KB h-plane ping-pong

  const int tid  = threadIdx.x;
  const int lane = tid & 63;
  const int wid  = tid >> 6;
  const int a    = lane & 15;   // D col = batch ; A/B free idx
  const int q    = lane >> 4;   // k subgroup ; D row-quad
  const int b0   = blockIdx.x * NB;

  // tile ownership: 13 gate-row tiles (rho' = 16*tile + a, rho' = 4*u + g), wave7 also head
  int t0 = -1, t1 = -1;
  switch (wid) {
    case 0: t0 = 0;  t1 = 1;  break;
    case 1: t0 = 4;  t1 = 5;  break;
    case 2: t0 = 7;  t1 = 8;  break;
    case 3: t0 = 10; t1 = 11; break;
    case 4: t0 = 2;  t1 = 3;  break;
    case 5: t0 = 6;  break;
    case 6: t0 = 9;  break;
    case 7: t0 = 12; break;
  }
  const bool isHead = (wid == 7);

  // ---------------- init: build weight A-fragments in registers ----------------
  f16x8 wA1[2][2][2];   // [tile][sp][hi/lo]  layer1: Whh1 | Wih1 cols | bias1
  f16x8 wA2[2][4][2];   // [tile][sp][hi/lo]  layer2: sp<2 Wih2+bias2, sp>=2 Whh2
  f16x8 hA[2][2];       // head: Wlin + blin on row 0 (vs PH2 planes)

  // round A: Whh1 (+Wih1, bias1 direct from global; tiny)
  for (int i = tid; i < H4 * H; i += BLK) SW[i] = Whh1[i];
  __syncthreads();
#pragma unroll
  for (int i = 0; i < 2; ++i) {
    const int tt = (i == 0) ? t0 : t1;
    if (tt >= 0) {
      const int  rp   = 16 * tt + a;
      const bool vld  = (rp < H4);
      const int  wrow = (rp & 3) * H + (rp >> 2);   // gate-major weight row
#pragma unroll
      for (int sp = 0; sp < 2; ++sp)
#pragma unroll
        for (int j = 0; j < 8; ++j) {
          const int k = 32 * sp + 16 * (j >> 2) + 4 * q + (j & 3);
          float val = 0.f;
          if (vld) {
            if (k < H)          val = SW[wrow * H + k];
            else if (k == H)    val = Wih1[wrow * 2 + 0];
            else if (k == H + 1) val = Wih1[wrow * 2 + 1];
            else if (k == H + 2) val = bih1[wrow] + bhh1[wrow];
          }
          const _Float16 hi = (_Float16)val;
          wA1[i][sp][0][j] = hi;
          wA1[i][sp][1][j] = (_Float16)(val - (float)hi);
        }
    }
  }
  __syncthreads();
  // round B: Wih2 (+bias2)
  for (int i = tid; i < H4 * H; i += BLK) SW[i] = Wih2[i];
  __syncthreads();
#pragma unroll
  for (int i = 0; i < 2; ++i) {
    const int tt = (i == 0) ? t0 : t1;
    if (tt >= 0) {
      const int  rp   = 16 * tt + a;
      const bool vld  = (rp < H4);
      const int  wrow = (rp & 3) * H + (rp >> 2);
#pragma unroll
      for (int sp = 0; sp < 2; ++sp)
#pragma unroll
        for (int j = 0; j < 8; ++j) {
          const int k = 32 * sp + 16 * (j >> 2) + 4 * q + (j & 3);
          float val = 0.f;
          if (vld) {
            if (k < H)           val = SW[wrow * H + k];
            else if (k == H + 2) val = bih2[wrow] + bhh2[wrow];
          }
          const _Float16 hi = (_Float16)val;
          wA2[i][sp][0][j] = hi;
          wA2[i][sp][1][j] = (_Float16)(val - (float)hi);
        }
    }
  }
  __syncthreads();
  // round C: Whh2
  for (int i = tid; i < H4 * H; i += BLK) SW[i] = Whh2[i];
  __syncthreads();
#pragma unroll
  for (int i = 0; i < 2; ++i) {
    const int tt = (i == 0) ? t0 : t1;
    if (tt >= 0) {
      const int  rp   = 16 * tt + a;
      const bool vld  = (rp < H4);
      const int  wrow = (rp & 3) * H + (rp >> 2);
#pragma unroll
      for (int sp = 2; sp < 4; ++sp)
#pragma unroll
        for (int j = 0; j < 8; ++j) {
          const int kp = 32 * (sp - 2) + 16 * (j >> 2) + 4 * q + (j & 3);
          float val = (vld && kp < H) ? SW[wrow * H + kp] : 0.f;
          const _Float16 hi = (_Float16)val;
          wA2[i][sp][0][j] = hi;
          wA2[i][sp][1][j] = (_Float16)(val - (float)hi);
        }
    }
  }
  // head fragments (row 0 only)
  if (isHead) {
#pragma unroll
    for (int sp = 0; sp < 2; ++sp)
#pragma unroll
      for (int j = 0; j < 8; ++j) {
        const int kp = 32 * sp + 16 * (j >> 2) + 4 * q + (j & 3);
        float val = 0.f;
        if (a == 0) {
          if (kp < H)           val = Wlin[kp];
          else if (kp == H + 2) val = blin[0];
        }
        const _Float16 hi = (_Float16)val;
        hA[sp][0][j] = hi;
        hA[sp][1][j] = (_Float16)(val - (float)hi);
      }
  }

  // ---------------- init planes: zeros + const-1 slots + x(0) ----------------
  __syncthreads();
  for (int i = tid; i < 4096; i += BLK) PL[i] = 0;
  __syncthreads();
  if (tid < 16) {
    // k=53 -> sp=1, row=b+16, j=5 ; set "1" in both buffers, both layers
#pragma unroll
    for (int buf = 0; buf < 2; ++buf) {
      PL[(buf * 4 + 0 * 2 + 1) * 512 + (tid + 16) * 8 + 5] = 0x3C00;  // fp16 1.0
      PL[(buf * 4 + 1 * 2 + 1) * 512 + (tid + 16) * 8 + 5] = 0x3C00;
    }
  }
  float xw = 0.f;
  if (isHead && lane < 32) {
    const int bb = lane & 15, f = lane >> 4;
    const float x0v = x[(size_t)(b0 + bb) * 2 + f];
    // x slots: x0 -> k=51 (sp=1,row=b,j=7) ; x1 -> k=52 (sp=1,row=b+16,j=4); buf0
    const int idx = (0 * 4 + 0 * 2 + 1) * 512 + ((f == 0) ? bb * 8 + 7 : (bb + 16) * 8 + 4);
    *(_Float16*)&PL[idx] = (_Float16)x0v;
    xw = x[(size_t)Bsz * 2 + (size_t)(b0 + bb) * 2 + f];  // x(1), written during slot 0
  }
  __syncthreads();

  // ---------------- main loop: T+2 slots, 1 barrier each ----------------
  // slot s: MFMA gates1(t=s) & gates2(t2=s-1) & head(th=s-2) from planes[buf=s&1];
  //         act1 -> h1(s), act2 -> h2(s-1), x(s+1) written into planes[buf^1].
  float c1[2] = {0.f, 0.f}, c2[2] = {0.f, 0.f};

  for (int s = 0; s < T + 2; ++s) {
    const int pb = (s & 1) * 2048;      // read buffer base (shorts)
    const int nb = 2048 - pb;           // write buffer base

    // B-fragments: PH1 sp0, PH1 sp1, PH2 sp0, PH2 sp1
    f16x8 bh[4];
#pragma unroll
    for (int p = 0; p < 4; ++p)
      bh[p] = *(const f16x8*)&PL[pb + p * 512 + lane * 8];

    // prefetch x(s+2) (head wave only)
    float xf = 0.f;
    if (isHead && lane < 32) {
      const int bb = lane & 15, f = lane >> 4;
      int tx = s + 2; if (tx > T - 1) tx = T - 1;
      xf = x[(size_t)tx * Bsz * 2 + (size_t)(b0 + bb) * 2 + f];
    }

    // MFMA: D = W(hi)*h + W(lo)*h, accumulators fp32
    f32x4 d1[2], d2[2];
#pragma unroll
    for (int i = 0; i < 2; ++i) {
      const int tt = (i == 0) ? t0 : t1;
      if (tt >= 0) {
        f32x4 acc = {0.f, 0.f, 0.f, 0.f};
#pragma unroll
        for (int sp = 0; sp < 2; ++sp) {
          acc = __builtin_amdgcn_mfma_f32_16x16x32_f16(wA1[i][sp][0], bh[sp], acc, 0, 0, 0);
          acc = __builtin_amdgcn_mfma_f32_16x16x32_f16(wA1[i][sp][1], bh[sp], acc, 0, 0, 0);
        }
        d1[i] = acc;
        f32x4 acc2 = {0.f, 0.f, 0.f, 0.f};
#pragma unroll
        for (int sp = 0; sp < 4; ++sp) {
          acc2 = __builtin_amdgcn_mfma_f32_16x16x32_f16(wA2[i][sp][0], bh[sp], acc2, 0, 0, 0);
          acc2 = __builtin_amdgcn_mfma_f32_16x16x32_f16(wA2[i][sp][1], bh[sp], acc2, 0, 0, 0);
        }
        d2[i] = acc2;
      }
    }

    // activations + h-plane writes (lane owns u = 4*tile + q, batch = a, gates p=0..3)
    const bool doA1 = (s < T);
    const bool doA2 = (s >= 1 && s <= T);
#pragma unroll
    for (int i = 0; i < 2; ++i) {
      const int tt = (i == 0) ? t0 : t1;
      if (tt >= 0) {
        const int  u    = 4 * tt + q;
        const bool uval = (u < H);
        const int  spl  = u >> 5, kl = u & 31;
        const int  row  = a + 16 * ((kl >> 2) & 3);
        const int  jj   = (kl & 3) + 4 * (kl >> 4);
        const int  widx = nb + spl * 512 + row * 8 + jj;   // layer-1 plane slot
        if (doA1) {
          const float h1 = lstm_act(d1[i][0], d1[i][1], d1[i][2], d1[i][3], c1[i]);
          if (uval) *(_Float16*)&PL[widx] = (_Float16)h1;
        }
        if (doA2) {
          const float h2 = lstm_act(d2[i][0], d2[i][1], d2[i][2], d2[i][3], c2[i]);
          if (uval) *(_Float16*)&PL[widx + 1024] = (_Float16)h2;  // layer-2 planes
        }
      }
    }

    // head: out(th=s-2) = Wlin . h2(s-2) + blin ; plus x(s+1) injection
    if (isHead) {
      f32x4 dh = {0.f, 0.f, 0.f, 0.f};
      dh = __builtin_amdgcn_mfma_f32_16x16x32_f16(hA[0][0], bh[2], dh, 0, 0, 0);
      dh = __builtin_amdgcn_mfma_f32_16x16x32_f16(hA[0][1], bh[2], dh, 0, 0, 0);
      dh = __builtin_amdgcn_mfma_f32_16x16x32_f16(hA[1][0], bh[3], dh, 0, 0, 0);
      dh = __builtin_amdgcn_mfma_f32_16x16x32_f16(hA[1][1], bh[3], dh, 0, 0, 0);
      if (s >= 2 && lane < 16)
        out[(size_t)(b0 + a) * T + (s - 2)] = dh[0];
      if (lane < 32 && s + 1 < T) {
        const int bb = lane & 15, f = lane >> 4;
        const int idx = nb + 512 + ((f == 0) ? bb * 8 + 7 : (bb + 16) * 8 + 4);
        *(_Float16*)&PL[idx] = (_Float16)xw;
      }
      xw = xf;
    }
    __syncthreads();
  }
}

extern "C" void kernel_launch(void* const* d_in, const int* in_sizes, int n_in,
                              void* d_out, int out_size, void* d_ws, size_t ws_size,
                              hipStream_t stream) {
  (void)in_sizes; (void)n_in; (void)d_ws; (void)ws_size; (void)out_size;
  const float* x    = (const float*)d_in[0];
  const float* Wih1 = (const float*)d_in[1];
  const float* Whh1 = (const float*)d_in[2];
  const float* bih1 = (const float*)d_in[3];
  const float* bhh1 = (const float*)d_in[4];
  const float* Wih2 = (const float*)d_in[5];
  const float* Whh2 = (const float*)d_in[6];
  const float* bih2 = (const float*)d_in[7];
  const float* bhh2 = (const float*)d_in[8];
  const float* Wlin = (const float*)d_in[9];
  const float* blin = (const float*)d_in[10];
  float* out = (float*)d_out;

  hipLaunchKernelGGL(lstm2_v3, dim3(GRID), dim3(BLK), 0, stream,
                     x, Wih1, Whh1, bih1, bhh1, Wih2, Whh2, bih2, bhh2,
                     Wlin, blin, out);
}